// Round 3
// baseline (198.925 us; speedup 1.0000x reference)
//
#include <hip/hip_runtime.h>
#include <hip/hip_bf16.h>
#include <stdint.h>

// AutoregressiveDense: B=8192, D=1024, STRIDE=16, OUT=64, L=64
#define BROWS 8192
#define DDIM  1024
#define LDIM  64
#define ODIM  64
#define NDIM  4096
#define KSTRIDE 16

typedef __attribute__((ext_vector_type(8))) short bf16x8;           // MFMA A/B frag
typedef __attribute__((ext_vector_type(4))) float f32x4;            // MFMA C/D frag
typedef __attribute__((ext_vector_type(8))) unsigned short u16x8;   // 16B bf16 store

static __device__ __forceinline__ unsigned short f2bf(float f) {
    union { float f; uint32_t u; } v; v.f = f;
    uint32_t r = 0x7FFFu + ((v.u >> 16) & 1u);
    return (unsigned short)((v.u + r) >> 16);
}

static __device__ __forceinline__ void async16(const void* g, void* l) {
    __builtin_amdgcn_global_load_lds(
        (const __attribute__((address_space(1))) void*)g,
        (__attribute__((address_space(3))) void*)l, 16, 0, 0);
}

// ---------- merged prep: blocks [0,1024) build masked W' (B^T bf16), blocks [1024,5120) convert x ----------
__global__ __launch_bounds__(256) void prep_kernel(const float* __restrict__ x,
                                                   const float* __restrict__ W,
                                                   unsigned short* __restrict__ xb,
                                                   unsigned short* __restrict__ wbt) {
    const int bid = blockIdx.x;
    if (bid < 1024) {
        // W [L][D][O] f32 -> masked bf16 W' [N=l*64+o][K=d], zero for d >= l*16
        __shared__ float tile[64][65];
        const int l  = bid >> 4;
        const int d0 = (bid & 15) << 6;
        const int t  = threadIdx.x;
        {
            const int dd = t >> 2;
            const int o4 = (t & 3) << 4;
            const float* src = W + ((size_t)((l << 10) + d0 + dd) << 6) + o4;
            #pragma unroll
            for (int j = 0; j < 4; ++j) {
                float4 v = reinterpret_cast<const float4*>(src)[j];
                tile[dd][o4 + 4 * j + 0] = v.x;
                tile[dd][o4 + 4 * j + 1] = v.y;
                tile[dd][o4 + 4 * j + 2] = v.z;
                tile[dd][o4 + 4 * j + 3] = v.w;
            }
        }
        __syncthreads();
        {
            const int o    = t >> 2;
            const int dloc = (t & 3) << 4;
            const int kmax = l * KSTRIDE;
            unsigned short* dst = wbt + ((size_t)((l << 6) + o) << 10) + d0 + dloc;
            u16x8 r0, r1;
            #pragma unroll
            for (int j = 0; j < 8; ++j) {
                int da = d0 + dloc + j;
                int db = da + 8;
                r0[j] = (da < kmax) ? f2bf(tile[dloc + j][o])     : (unsigned short)0;
                r1[j] = (db < kmax) ? f2bf(tile[dloc + 8 + j][o]) : (unsigned short)0;
            }
            *reinterpret_cast<u16x8*>(dst)     = r0;
            *reinterpret_cast<u16x8*>(dst + 8) = r1;
        }
    } else {
        int i = (bid - 1024) * 256 + threadIdx.x;
        const float4* xf = reinterpret_cast<const float4*>(x);
        float4 v0 = xf[2 * i];
        float4 v1 = xf[2 * i + 1];
        u16x8 r;
        r[0] = f2bf(v0.x); r[1] = f2bf(v0.y); r[2] = f2bf(v0.z); r[3] = f2bf(v0.w);
        r[4] = f2bf(v1.x); r[5] = f2bf(v1.y); r[6] = f2bf(v1.z); r[7] = f2bf(v1.w);
        reinterpret_cast<u16x8*>(xb)[i] = r;
    }
}

// ---------- main GEMM: 256x256 tile, BK=64, 8 waves (2Mx4N), 8-phase counted-vmcnt schedule ----------
// A = xb [8192][1024] bf16; B^T = wbt [4096][1024] bf16. nkt = bn+1 K-tiles of 64.
// LDS 128KB: buffer par in {0,1}: A at par*65536 (256 rows x 128B, XOR-swizzled), B at par*65536+32768.
// Swizzle: byte ^= ((row&7)<<4); staged via inverse-swizzled GLOBAL source + linear gload_lds dest.
#define MMQ(I0, J0, B) \
    _Pragma("unroll") \
    for (int ii = 0; ii < 4; ++ii) \
    _Pragma("unroll") \
    for (int jj = 0; jj < 2; ++jj) \
    _Pragma("unroll") \
    for (int kk = 0; kk < 2; ++kk) \
        acc[(I0) + ii][(J0) + jj] = __builtin_amdgcn_mfma_f32_16x16x32_bf16( \
            a[ii][kk], B[jj][kk], acc[(I0) + ii][(J0) + jj], 0, 0, 0);

#define BAR_MID() do { __builtin_amdgcn_s_barrier(); \
    asm volatile("s_waitcnt lgkmcnt(0)" ::: "memory"); \
    __builtin_amdgcn_sched_barrier(0); } while (0)
#define BAR_END() do { __builtin_amdgcn_sched_barrier(0); \
    __builtin_amdgcn_s_barrier(); } while (0)
#define VMW4() asm volatile("s_waitcnt vmcnt(4)" ::: "memory")

// __launch_bounds__(512, 1): 1 wave/EU floor -> 256-VGPR budget. (512,2) resolved to a
// 128-VGPR cap and spilled the 128-reg accumulator to scratch (r2: WRITE_SIZE 674MB vs
// 134MB output, MfmaUtil 7.5%). LDS (128KB) limits to 1 block/CU regardless.
__global__ __launch_bounds__(512, 1) void ar_gemm_kernel(
        const unsigned short* __restrict__ xb,
        const unsigned short* __restrict__ wbt,
        const float* __restrict__ bias,
        float* __restrict__ out) {
    __shared__ int4 smem[8192];   // 128 KiB
    char* ldsc = (char*)smem;

    const int tid  = threadIdx.x;
    const int lane = tid & 63;
    const int wid  = tid >> 6;
    const int wm   = wid >> 2;          // 2 M-waves x 4 N-waves; wave tile 128x64
    const int wn   = wid & 3;
    const int bid  = blockIdx.x;
    const int bm   = bid & 31;
    const int bn   = 15 - (bid >> 5);   // heavy K-loops dispatch first
    const int nkt  = bn + 1;            // K-tiles of 64 (covers (4bn+3)*16)

    // staging constants: thread t stages LDS-linear o=t*16 (+8192); global granule inverse-swizzled
    const int gcol = (((tid & 7) ^ ((tid >> 3) & 7)) << 4);
    const int srow = tid >> 3;

    // ds_read swizzled granule bytes for kk=0,1: granule=(kk<<2)|(lane>>4), XOR row&7 (= lane&7)
    const int g0 = (((lane >> 4)     ^ (lane & 7)) << 4);
    const int g1 = (((4 | (lane >> 4)) ^ (lane & 7)) << 4);
    const int aoff = (wm * 128 + (lane & 15)) * 128;
    const int boff = 32768 + (wn * 64 + (lane & 15)) * 128;

    f32x4 acc[8][4];
    #pragma unroll
    for (int i = 0; i < 8; ++i)
        #pragma unroll
        for (int j = 0; j < 4; ++j)
            acc[i][j] = (f32x4)(0.f);

    bf16x8 a[4][2], bL[2][2], bH[2][2];

    // part: 0=A-half0, 1=A-half1, 2=B-half0, 3=B-half1. Out-of-range t -> clamp SOURCE only
    // (dest region is free by the schedule; data unused). Keeps vmcnt counts uniform.
    auto stage = [&](int t, int part) {
        const int ts = t < nkt ? t : nkt - 1;
        char* l = ldsc + ((t & 1) << 16) + ((part >> 1) << 15) + ((part & 1) << 14) + tid * 16;
        const unsigned short* srcm = (part >= 2) ? wbt : xb;
        const int rb = (((part >= 2) ? bn : bm) << 8) + ((part & 1) << 7) + srow;
        const char* g = (const char*)srcm + ((size_t)rb << 11) + ts * 128 + gcol;
        async16(g, l);
        async16(g + (64 << 11), l + 8192);
    };
    auto readA = [&](int par, int ih) {
        const char* p = ldsc + (par << 16) + aoff + (ih << 13);
        #pragma unroll
        for (int ii = 0; ii < 4; ++ii) {
            a[ii][0] = *(const bf16x8*)(p + ii * 2048 + g0);
            a[ii][1] = *(const bf16x8*)(p + ii * 2048 + g1);
        }
    };
    auto readB = [&](int par, int jh, bf16x8 (&b)[2][2]) {
        const char* p = ldsc + (par << 16) + boff + (jh << 12);
        #pragma unroll
        for (int jj = 0; jj < 2; ++jj) {
            b[jj][0] = *(const bf16x8*)(p + jj * 2048 + g0);
            b[jj][1] = *(const bf16x8*)(p + jj * 2048 + g1);
        }
    };

    // prologue: tile0 fully + B halves of tile1 (matches steady-state rotation entry)
    stage(0, 0); stage(0, 1); stage(0, 2); stage(0, 3);
    stage(1, 2); stage(1, 3);
    VMW4();                       // drain tile0's 8 loads; B(1) stays in flight
    __builtin_amdgcn_s_barrier();

    const int niter = (nkt + 1) >> 1;
    for (int J = 0; J < niter; ++J) {
        const int T2 = 2 * J;
        // P1: quadrant (i0-3, j0-1) of tile T2 (buffer0)
        readA(0, 0); readB(0, 0, bL);
        stage(T2 + 1, 0);
        BAR_MID();
        __builtin_amdgcn_s_setprio(1); MMQ(0, 0, bL); __builtin_amdgcn_s_setprio(0);
        BAR_END();
        // P2: (i0-3, j2-3)
        readB(0, 1, bH);
        stage(T2 + 1, 1);
        BAR_MID();
        __builtin_amdgcn_s_setprio(1); MMQ(0, 2, bH); __builtin_amdgcn_s_setprio(0);
        BAR_END();
        // P3: (i4-7, j2-3)
        readA(0, 1);
        stage(T2 + 2, 2);
        BAR_MID();
        __builtin_amdgcn_s_setprio(1); MMQ(4, 2, bH); __builtin_amdgcn_s_setprio(0);
        BAR_END();
        // P4: (i4-7, j0-1); counted vmcnt guards tile T2+1 for P5
        stage(T2 + 2, 3);
        VMW4();
        BAR_MID();
        __builtin_amdgcn_s_setprio(1); MMQ(4, 0, bL); __builtin_amdgcn_s_setprio(0);
        BAR_END();
        if (T2 + 1 >= nkt) break;   // odd-nkt tail: tile nkt-1 done in P1-P4
        // P5: tile T2+1 (buffer1), (i0-3, j0-1)
        readA(1, 0); readB(1, 0, bL);
        stage(T2 + 2, 0);
        BAR_MID();
        __builtin_amdgcn_s_setprio(1); MMQ(0, 0, bL); __builtin_amdgcn_s_setprio(0);
        BAR_END();
        // P6: (i0-3, j2-3)
        readB(1, 1, bH);
        stage(T2 + 2, 1);
        BAR_MID();
        __builtin_amdgcn_s_setprio(1); MMQ(0, 2, bH); __builtin_amdgcn_s_setprio(0);
        BAR_END();
        // P7: (i4-7, j2-3)
        readA(1, 1);
        stage(T2 + 3, 2);
        BAR_MID();
        __builtin_amdgcn_s_setprio(1); MMQ(4, 2, bH); __builtin_amdgcn_s_setprio(0);
        BAR_END();
        // P8: (i4-7, j0-1); counted vmcnt guards tiles T2+2/T2+3 for next iter
        stage(T2 + 3, 3);
        VMW4();
        BAR_MID();
        __builtin_amdgcn_s_setprio(1); MMQ(4, 0, bL); __builtin_amdgcn_s_setprio(0);
        BAR_END();
    }

    // epilogue: C/D layout col=lane&15, row=(lane>>4)*4+q; bias[col] add in f32
    const int crow0 = (bm << 8) + (wm << 7) + ((lane >> 4) << 2);
    const int ccol  = (bn << 8) + (wn << 6) + (lane & 15);
    float bv[4];
    #pragma unroll
    for (int j = 0; j < 4; ++j) bv[j] = bias[ccol + j * 16];
    #pragma unroll
    for (int i = 0; i < 8; ++i)
        #pragma unroll
        for (int j = 0; j < 4; ++j)
            #pragma unroll
            for (int q = 0; q < 4; ++q)
                out[(size_t)(crow0 + i * 16 + q) * NDIM + ccol + j * 16] = acc[i][j][q] + bv[j];
}

// ---------- fallback: naive f32 (used only if workspace too small) ----------
__global__ __launch_bounds__(256) void naive_kernel(const float* __restrict__ x,
                                                    const float* __restrict__ W,
                                                    const float* __restrict__ bias,
                                                    float* __restrict__ out) {
    size_t idx = (size_t)blockIdx.x * 256 + threadIdx.x;
    if (idx >= (size_t)BROWS * NDIM) return;
    int m = (int)(idx >> 12);
    int n = (int)(idx & 4095);
    int l = n >> 6;
    int o = n & 63;
    int kmax = l * KSTRIDE;
    float s = bias[n];
    const float* xr = x + (size_t)m * DDIM;
    const float* wp = W + ((size_t)l << 16) + o;
    for (int d = 0; d < kmax; ++d) s += xr[d] * wp[(size_t)d << 6];
    out[idx] = s;
}

extern "C" void kernel_launch(void* const* d_in, const int* in_sizes, int n_in,
                              void* d_out, int out_size, void* d_ws, size_t ws_size,
                              hipStream_t stream) {
    const float* x = (const float*)d_in[0];
    const float* W = (const float*)d_in[1];
    const float* b = (const float*)d_in[2];
    float* out = (float*)d_out;

    const size_t need = ((size_t)BROWS * DDIM + (size_t)NDIM * DDIM) * sizeof(unsigned short);
    if (ws_size < need) {
        int total = BROWS * NDIM;
        naive_kernel<<<(total + 255) / 256, 256, 0, stream>>>(x, W, b, out);
        return;
    }
    unsigned short* xbuf = (unsigned short*)d_ws;             // bf16 x  [8192][1024]
    unsigned short* wbt  = xbuf + (size_t)BROWS * DDIM;       // bf16 W' [4096][1024]

    prep_kernel<<<5120, 256, 0, stream>>>(x, W, xbuf, wbt);
    ar_gemm_kernel<<<512, 512, 0, stream>>>(xbuf, wbt, b, out);
}

// Round 4
// 75.909 us; speedup vs baseline: 2.6206x; 2.6206x over previous
//
#include <hip/hip_runtime.h>
#include <hip/hip_bf16.h>
#include <stdint.h>

// AutoregressiveDense: B=8192, D=1024, STRIDE=16, OUT=64, L=64
#define BROWS 8192
#define DDIM  1024
#define LDIM  64
#define ODIM  64
#define NDIM  4096
#define KSTRIDE 16

typedef __attribute__((ext_vector_type(8))) short bf16x8;           // MFMA A/B frag
typedef __attribute__((ext_vector_type(4))) float f32x4;            // MFMA C/D frag
typedef __attribute__((ext_vector_type(8))) unsigned short u16x8;   // 16B bf16 store

static __device__ __forceinline__ unsigned short f2bf(float f) {
    union { float f; uint32_t u; } v; v.f = f;
    uint32_t r = 0x7FFFu + ((v.u >> 16) & 1u);
    return (unsigned short)((v.u + r) >> 16);
}

static __device__ __forceinline__ void async16(const void* g, void* l) {
    __builtin_amdgcn_global_load_lds(
        (const __attribute__((address_space(1))) void*)g,
        (__attribute__((address_space(3))) void*)l, 16, 0, 0);
}

// ---------- merged prep: blocks [0,1024) build masked W' (B^T bf16), blocks [1024,5120) convert x ----------
__global__ __launch_bounds__(256) void prep_kernel(const float* __restrict__ x,
                                                   const float* __restrict__ W,
                                                   unsigned short* __restrict__ xb,
                                                   unsigned short* __restrict__ wbt) {
    const int bid = blockIdx.x;
    if (bid < 1024) {
        // W [L][D][O] f32 -> masked bf16 W' [N=l*64+o][K=d], zero for d >= l*16
        __shared__ float tile[64][65];
        const int l  = bid >> 4;
        const int d0 = (bid & 15) << 6;
        const int t  = threadIdx.x;
        {
            const int dd = t >> 2;
            const int o4 = (t & 3) << 4;
            const float* src = W + ((size_t)((l << 10) + d0 + dd) << 6) + o4;
            #pragma unroll
            for (int j = 0; j < 4; ++j) {
                float4 v = reinterpret_cast<const float4*>(src)[j];
                tile[dd][o4 + 4 * j + 0] = v.x;
                tile[dd][o4 + 4 * j + 1] = v.y;
                tile[dd][o4 + 4 * j + 2] = v.z;
                tile[dd][o4 + 4 * j + 3] = v.w;
            }
        }
        __syncthreads();
        {
            const int o    = t >> 2;
            const int dloc = (t & 3) << 4;
            const int kmax = l * KSTRIDE;
            unsigned short* dst = wbt + ((size_t)((l << 6) + o) << 10) + d0 + dloc;
            u16x8 r0, r1;
            #pragma unroll
            for (int j = 0; j < 8; ++j) {
                int da = d0 + dloc + j;
                int db = da + 8;
                r0[j] = (da < kmax) ? f2bf(tile[dloc + j][o])     : (unsigned short)0;
                r1[j] = (db < kmax) ? f2bf(tile[dloc + 8 + j][o]) : (unsigned short)0;
            }
            *reinterpret_cast<u16x8*>(dst)     = r0;
            *reinterpret_cast<u16x8*>(dst + 8) = r1;
        }
    } else {
        int i = (bid - 1024) * 256 + threadIdx.x;
        const float4* xf = reinterpret_cast<const float4*>(x);
        float4 v0 = xf[2 * i];
        float4 v1 = xf[2 * i + 1];
        u16x8 r;
        r[0] = f2bf(v0.x); r[1] = f2bf(v0.y); r[2] = f2bf(v0.z); r[3] = f2bf(v0.w);
        r[4] = f2bf(v1.x); r[5] = f2bf(v1.y); r[6] = f2bf(v1.z); r[7] = f2bf(v1.w);
        reinterpret_cast<u16x8*>(xb)[i] = r;
    }
}

// ---------- main GEMM: 256x128 tile, BK=64, 8 waves (2Mx4N, wave tile 128x32) ----------
// acc[8][2] = 64 regs/thread: r2/r3 spilled with acc[8][4]=128 (WRITE_SIZE 674MB vs 134MB
// output = 2KB/thread scratch). Halving per-wave N kills the spill; schedule unchanged.
// LDS 96KB: A buffers at par<<15 (256 rows x 128B swizzled), B at 65536 + (par<<14) (128 rows).
// Swizzle: byte ^= ((row&7)<<4) via inverse-swizzled GLOBAL source + swizzled ds_read.
#define MMQ(I0) \
    _Pragma("unroll") \
    for (int ii = 0; ii < 4; ++ii) \
    _Pragma("unroll") \
    for (int jj = 0; jj < 2; ++jj) \
    _Pragma("unroll") \
    for (int kk = 0; kk < 2; ++kk) \
        acc[(I0) + ii][jj] = __builtin_amdgcn_mfma_f32_16x16x32_bf16( \
            a[ii][kk], bfr[jj][kk], acc[(I0) + ii][jj], 0, 0, 0);

#define BAR_MID() do { __builtin_amdgcn_s_barrier(); \
    asm volatile("s_waitcnt lgkmcnt(0)" ::: "memory"); \
    __builtin_amdgcn_sched_barrier(0); } while (0)
#define BAR_END() do { __builtin_amdgcn_sched_barrier(0); \
    __builtin_amdgcn_s_barrier(); } while (0)
#define VMW2() asm volatile("s_waitcnt vmcnt(2)" ::: "memory")

__global__ __launch_bounds__(512)
__attribute__((amdgpu_waves_per_eu(2, 2)))
void ar_gemm_kernel(const unsigned short* __restrict__ xb,
                    const unsigned short* __restrict__ wbt,
                    const float* __restrict__ bias,
                    float* __restrict__ out) {
    __shared__ int4 smem[6144];   // 96 KiB
    char* ldsc = (char*)smem;

    const int tid  = threadIdx.x;
    const int lane = tid & 63;
    const int wid  = tid >> 6;
    const int wm   = wid >> 2;          // 2 M-waves x 4 N-waves; wave tile 128x32
    const int wn   = wid & 3;
    const int bid  = blockIdx.x;
    const int bm   = bid & 31;
    const int bn   = 31 - (bid >> 5);   // heavy K-loops dispatch first
    const int nkt  = (bn + 2) >> 1;     // ceil((2bn+1)*16 / 64), 1..16

    // staging: thread t writes LDS-linear t*16 (+8192); global granule inverse-swizzled
    const int gcol = (((tid & 7) ^ ((tid >> 3) & 7)) << 4);
    const int srow = tid >> 3;

    // swizzled ds_read granule bytes for kk=0,1 (row&7 == lane&7 for all frag rows)
    const int g0 = (((lane >> 4)       ^ (lane & 7)) << 4);
    const int g1 = (((4 | (lane >> 4)) ^ (lane & 7)) << 4);
    const int aoff = (wm * 128 + (lane & 15)) * 128;
    const int boff = (wn * 32 + (lane & 15)) * 128;

    f32x4 acc[8][2];
    #pragma unroll
    for (int i = 0; i < 8; ++i)
        #pragma unroll
        for (int j = 0; j < 2; ++j)
            acc[i][j] = (f32x4)(0.f);

    bf16x8 a[4][2], bfr[2][2];

    // parts: 0 = A rows 0-127, 1 = A rows 128-255, 2 = B rows 0-127.
    // Out-of-range t: clamp SOURCE only (dest slot free by schedule; data unused).
    auto stage = [&](int t, int part) {
        const int ts = t < nkt ? t : nkt - 1;
        char* l = ldsc + ((part == 2) ? (65536 + ((t & 1) << 14))
                                      : (((t & 1) << 15) + (part << 14))) + tid * 16;
        const unsigned short* srcm = (part == 2) ? wbt : xb;
        const int rb = ((part == 2) ? (bn << 7) : ((bm << 8) + (part << 7))) + srow;
        const char* g = (const char*)srcm + ((size_t)rb << 11) + ts * 128 + gcol;
        async16(g, l);
        async16(g + (64 << 11), l + 8192);
    };
    auto readA = [&](int par, int ih) {
        const char* p = ldsc + (par << 15) + aoff + (ih << 13);
        #pragma unroll
        for (int ii = 0; ii < 4; ++ii) {
            a[ii][0] = *(const bf16x8*)(p + ii * 2048 + g0);
            a[ii][1] = *(const bf16x8*)(p + ii * 2048 + g1);
        }
    };
    auto readB = [&](int par) {
        const char* p = ldsc + 65536 + (par << 14) + boff;
        #pragma unroll
        for (int jj = 0; jj < 2; ++jj) {
            bfr[jj][0] = *(const bf16x8*)(p + jj * 2048 + g0);
            bfr[jj][1] = *(const bf16x8*)(p + jj * 2048 + g1);
        }
    };

    // prologue: tile0 complete + tile1's B; vmcnt(2) leaves tile1-B in flight
    stage(0, 2); stage(0, 0); stage(0, 1); stage(1, 2);
    VMW2();
    __builtin_amdgcn_s_barrier();

    for (int J = 0;; ++J) {
        const int T = 2 * J;
        // P1: tile T (buf0), i0-3
        readA(0, 0); readB(0);
        stage(T + 1, 0);
        BAR_MID();
        __builtin_amdgcn_s_setprio(1); MMQ(0); __builtin_amdgcn_s_setprio(0);
        BAR_END();
        // P2: tile T, i4-7; vmcnt(2) drains tile T+1 (B,Alo,Ahi), leaves T+2-B
        readA(0, 1);
        stage(T + 1, 1); stage(T + 2, 2);
        VMW2();
        BAR_MID();
        __builtin_amdgcn_s_setprio(1); MMQ(4); __builtin_amdgcn_s_setprio(0);
        BAR_END();
        if (T + 1 >= nkt) break;
        // P3: tile T+1 (buf1), i0-3
        readA(1, 0); readB(1);
        stage(T + 2, 0);
        BAR_MID();
        __builtin_amdgcn_s_setprio(1); MMQ(0); __builtin_amdgcn_s_setprio(0);
        BAR_END();
        // P4: tile T+1, i4-7; vmcnt(2) drains tile T+2, leaves T+3-B
        readA(1, 1);
        stage(T + 2, 1); stage(T + 3, 2);
        VMW2();
        BAR_MID();
        __builtin_amdgcn_s_setprio(1); MMQ(4); __builtin_amdgcn_s_setprio(0);
        BAR_END();
        if (T + 2 >= nkt) break;
    }

    // epilogue: C/D layout col=lane&15, row=(lane>>4)*4+q; bias[col] in f32
    const int crow0 = (bm << 8) + (wm << 7) + ((lane >> 4) << 2);
    const int ccol  = (bn << 7) + (wn << 5) + (lane & 15);
    float bv[2];
    #pragma unroll
    for (int j = 0; j < 2; ++j) bv[j] = bias[ccol + j * 16];
    #pragma unroll
    for (int i = 0; i < 8; ++i)
        #pragma unroll
        for (int j = 0; j < 2; ++j)
            #pragma unroll
            for (int q = 0; q < 4; ++q)
                out[(size_t)(crow0 + i * 16 + q) * NDIM + ccol + j * 16] = acc[i][j][q] + bv[j];
}

// ---------- fallback: naive f32 (used only if workspace too small) ----------
__global__ __launch_bounds__(256) void naive_kernel(const float* __restrict__ x,
                                                    const float* __restrict__ W,
                                                    const float* __restrict__ bias,
                                                    float* __restrict__ out) {
    size_t idx = (size_t)blockIdx.x * 256 + threadIdx.x;
    if (idx >= (size_t)BROWS * NDIM) return;
    int m = (int)(idx >> 12);
    int n = (int)(idx & 4095);
    int l = n >> 6;
    int o = n & 63;
    int kmax = l * KSTRIDE;
    float s = bias[n];
    const float* xr = x + (size_t)m * DDIM;
    const float* wp = W + ((size_t)l << 16) + o;
    for (int d = 0; d < kmax; ++d) s += xr[d] * wp[(size_t)d << 6];
    out[idx] = s;
}

extern "C" void kernel_launch(void* const* d_in, const int* in_sizes, int n_in,
                              void* d_out, int out_size, void* d_ws, size_t ws_size,
                              hipStream_t stream) {
    const float* x = (const float*)d_in[0];
    const float* W = (const float*)d_in[1];
    const float* b = (const float*)d_in[2];
    float* out = (float*)d_out;

    const size_t need = ((size_t)BROWS * DDIM + (size_t)NDIM * DDIM) * sizeof(unsigned short);
    if (ws_size < need) {
        int total = BROWS * NDIM;
        naive_kernel<<<(total + 255) / 256, 256, 0, stream>>>(x, W, b, out);
        return;
    }
    unsigned short* xbuf = (unsigned short*)d_ws;             // bf16 x  [8192][1024]
    unsigned short* wbt  = xbuf + (size_t)BROWS * DDIM;       // bf16 W' [4096][1024]

    prep_kernel<<<5120, 256, 0, stream>>>(x, W, xbuf, wbt);
    ar_gemm_kernel<<<1024, 512, 0, stream>>>(xbuf, wbt, b, out);
}

// Round 5
// 64.241 us; speedup vs baseline: 3.0965x; 1.1816x over previous
//
#include <hip/hip_runtime.h>
#include <hip/hip_bf16.h>
#include <stdint.h>

// AutoregressiveDense: B=8192, D=1024, STRIDE=16, OUT=64, L=64
#define BROWS 8192
#define DDIM  1024
#define LDIM  64
#define ODIM  64
#define NDIM  4096
#define KSTRIDE 16

typedef __attribute__((ext_vector_type(8))) short bf16x8;           // MFMA A/B frag
typedef __attribute__((ext_vector_type(4))) float f32x4;            // MFMA C/D frag
typedef __attribute__((ext_vector_type(8))) unsigned short u16x8;   // 16B bf16 store

static __device__ __forceinline__ unsigned short f2bf(float f) {
    union { float f; uint32_t u; } v; v.f = f;
    uint32_t r = 0x7FFFu + ((v.u >> 16) & 1u);
    return (unsigned short)((v.u + r) >> 16);
}

static __device__ __forceinline__ void async16(const void* g, void* l) {
    __builtin_amdgcn_global_load_lds(
        (const __attribute__((address_space(1))) void*)g,
        (__attribute__((address_space(3))) void*)l, 16, 0, 0);
}

// ---------- merged prep: blocks [0,1024) build masked W' (B^T bf16), blocks [1024,5120) convert x ----------
__global__ __launch_bounds__(256) void prep_kernel(const float* __restrict__ x,
                                                   const float* __restrict__ W,
                                                   unsigned short* __restrict__ xb,
                                                   unsigned short* __restrict__ wbt) {
    const int bid = blockIdx.x;
    if (bid < 1024) {
        // W [L][D][O] f32 -> masked bf16 W' [N=l*64+o][K=d], zero for d >= l*16
        __shared__ float tile[64][65];
        const int l  = bid >> 4;
        const int d0 = (bid & 15) << 6;
        const int t  = threadIdx.x;
        {
            const int dd = t >> 2;
            const int o4 = (t & 3) << 4;
            const float* src = W + ((size_t)((l << 10) + d0 + dd) << 6) + o4;
            #pragma unroll
            for (int j = 0; j < 4; ++j) {
                float4 v = reinterpret_cast<const float4*>(src)[j];
                tile[dd][o4 + 4 * j + 0] = v.x;
                tile[dd][o4 + 4 * j + 1] = v.y;
                tile[dd][o4 + 4 * j + 2] = v.z;
                tile[dd][o4 + 4 * j + 3] = v.w;
            }
        }
        __syncthreads();
        {
            const int o    = t >> 2;
            const int dloc = (t & 3) << 4;
            const int kmax = l * KSTRIDE;
            unsigned short* dst = wbt + ((size_t)((l << 6) + o) << 10) + d0 + dloc;
            u16x8 r0, r1;
            #pragma unroll
            for (int j = 0; j < 8; ++j) {
                int da = d0 + dloc + j;
                int db = da + 8;
                r0[j] = (da < kmax) ? f2bf(tile[dloc + j][o])     : (unsigned short)0;
                r1[j] = (db < kmax) ? f2bf(tile[dloc + 8 + j][o]) : (unsigned short)0;
            }
            *reinterpret_cast<u16x8*>(dst)     = r0;
            *reinterpret_cast<u16x8*>(dst + 8) = r1;
        }
    } else {
        int i = (bid - 1024) * 256 + threadIdx.x;
        const float4* xf = reinterpret_cast<const float4*>(x);
        float4 v0 = xf[2 * i];
        float4 v1 = xf[2 * i + 1];
        u16x8 r;
        r[0] = f2bf(v0.x); r[1] = f2bf(v0.y); r[2] = f2bf(v0.z); r[3] = f2bf(v0.w);
        r[4] = f2bf(v1.x); r[5] = f2bf(v1.y); r[6] = f2bf(v1.z); r[7] = f2bf(v1.w);
        reinterpret_cast<u16x8*>(xb)[i] = r;
    }
}

// ---------- main GEMM: 128x128 tile, BK=32, 4 waves (2x2) — round-1-proven structure ----------
// Only change vs round 1: bid -> (bm,bn) via 16x16 supertiles (256 blocks = one co-resident
// generation). bm fastest => XCD (= bid&7) sees 2 A-panels (1MB) x 16 B-panels (4MB) ~= its
// 4MB private L2 -> panel re-reads become L2 hits (r1 burned ~540MB logical reads through L3
// at ~11 TB/s service = the real r1 limiter). Heavy bn-supertile (bn 16-31) dispatches first.
__global__ __launch_bounds__(256, 2) void ar_gemm_kernel(
        const unsigned short* __restrict__ xb,
        const unsigned short* __restrict__ wbt,
        const float* __restrict__ bias,
        float* __restrict__ out) {
    __shared__ unsigned short As[128 * 32];   // [row][k] rows of 64B, linear (matches gload_lds)
    __shared__ unsigned short Bs[128 * 32];   // [col][k]

    const int s  = blockIdx.x >> 8;            // supertile 0..7 (4 bm-super x 2 bn-super)
    const int i  = blockIdx.x & 255;
    const int bm = ((s & 3) << 4) + (i & 15);          // 0..63
    const int bn = ((s < 4) ? 16 : 0) + 15 - (i >> 4); // heavy (16..31) first, big nkt first
    const int tid  = threadIdx.x;
    const int lane = tid & 63;
    const int wave = tid >> 6;
    const int wr   = wave >> 1;               // 2x2 wave grid, each wave owns 64x64
    const int wc   = wave & 1;

    const int nkt = ((2 * bn + 1) * KSTRIDE + 31) >> 5;   // = bn+1 K-tiles of 32

    // staging: each wave fills 2x 1KB chunks of As and Bs; lane order == linear LDS order
    const int rc = lane >> 2;            // row within a 16-row chunk
    const int cb = (lane & 3) << 4;      // byte col within the 64B row
    const char* gA0 = (const char*)xb  + ((size_t)(bm * 128 + (2 * wave + 0) * 16 + rc) * 2048) + cb;
    const char* gA1 = (const char*)xb  + ((size_t)(bm * 128 + (2 * wave + 1) * 16 + rc) * 2048) + cb;
    const char* gB0 = (const char*)wbt + ((size_t)(bn * 128 + (2 * wave + 0) * 16 + rc) * 2048) + cb;
    const char* gB1 = (const char*)wbt + ((size_t)(bn * 128 + (2 * wave + 1) * 16 + rc) * 2048) + cb;
    char* lA0 = (char*)As + (2 * wave + 0) * 1024;
    char* lA1 = (char*)As + (2 * wave + 1) * 1024;
    char* lB0 = (char*)Bs + (2 * wave + 0) * 1024;
    char* lB1 = (char*)Bs + (2 * wave + 1) * 1024;

    // fragment read offsets (bytes): row = (lane&15), k-halves by lane>>4
    const int aoff = ((wr << 6) + (lane & 15)) * 64 + ((lane >> 4) << 4);
    const int boff = ((wc << 6) + (lane & 15)) * 64 + ((lane >> 4) << 4);

    f32x4 acc[4][4];
    #pragma unroll
    for (int m = 0; m < 4; ++m)
        #pragma unroll
        for (int n = 0; n < 4; ++n)
            acc[m][n] = (f32x4)(0.f);

    for (int kt = 0; kt < nkt; ++kt) {
        const int kb = kt << 6;          // byte offset along K
        async16(gA0 + kb, lA0);
        async16(gA1 + kb, lA1);
        async16(gB0 + kb, lB0);
        async16(gB1 + kb, lB1);
        __syncthreads();
        bf16x8 a[4], b[4];
        #pragma unroll
        for (int m = 0; m < 4; ++m)
            a[m] = *reinterpret_cast<const bf16x8*>((const char*)As + aoff + m * 1024);
        #pragma unroll
        for (int n = 0; n < 4; ++n)
            b[n] = *reinterpret_cast<const bf16x8*>((const char*)Bs + boff + n * 1024);
        #pragma unroll
        for (int m = 0; m < 4; ++m)
            #pragma unroll
            for (int n = 0; n < 4; ++n)
                acc[m][n] = __builtin_amdgcn_mfma_f32_16x16x32_bf16(a[m], b[n], acc[m][n], 0, 0, 0);
        __syncthreads();
    }

    // epilogue: C/D layout col=lane&15, row=(lane>>4)*4+j; add bias in f32
    const int crow = (bm << 7) + (wr << 6) + ((lane >> 4) << 2);
    const int ccol = (bn << 7) + (wc << 6) + (lane & 15);
    float bv[4];
    #pragma unroll
    for (int n = 0; n < 4; ++n) bv[n] = bias[ccol + n * 16];
    #pragma unroll
    for (int m = 0; m < 4; ++m)
        #pragma unroll
        for (int n = 0; n < 4; ++n)
            #pragma unroll
            for (int j = 0; j < 4; ++j)
                out[(size_t)(crow + m * 16 + j) * NDIM + ccol + n * 16] = acc[m][n][j] + bv[n];
}

// ---------- fallback: naive f32 (used only if workspace too small) ----------
__global__ __launch_bounds__(256) void naive_kernel(const float* __restrict__ x,
                                                    const float* __restrict__ W,
                                                    const float* __restrict__ bias,
                                                    float* __restrict__ out) {
    size_t idx = (size_t)blockIdx.x * 256 + threadIdx.x;
    if (idx >= (size_t)BROWS * NDIM) return;
    int m = (int)(idx >> 12);
    int n = (int)(idx & 4095);
    int l = n >> 6;
    int o = n & 63;
    int kmax = l * KSTRIDE;
    float s = bias[n];
    const float* xr = x + (size_t)m * DDIM;
    const float* wp = W + ((size_t)l << 16) + o;
    for (int d = 0; d < kmax; ++d) s += xr[d] * wp[(size_t)d << 6];
    out[idx] = s;
}

extern "C" void kernel_launch(void* const* d_in, const int* in_sizes, int n_in,
                              void* d_out, int out_size, void* d_ws, size_t ws_size,
                              hipStream_t stream) {
    const float* x = (const float*)d_in[0];
    const float* W = (const float*)d_in[1];
    const float* b = (const float*)d_in[2];
    float* out = (float*)d_out;

    const size_t need = ((size_t)BROWS * DDIM + (size_t)NDIM * DDIM) * sizeof(unsigned short);
    if (ws_size < need) {
        int total = BROWS * NDIM;
        naive_kernel<<<(total + 255) / 256, 256, 0, stream>>>(x, W, b, out);
        return;
    }
    unsigned short* xbuf = (unsigned short*)d_ws;             // bf16 x  [8192][1024]
    unsigned short* wbt  = xbuf + (size_t)BROWS * DDIM;       // bf16 W' [4096][1024]

    prep_kernel<<<5120, 256, 0, stream>>>(x, W, xbuf, wbt);
    ar_gemm_kernel<<<2048, 256, 0, stream>>>(xbuf, wbt, b, out);
}

// Round 6
// 63.989 us; speedup vs baseline: 3.1088x; 1.0040x over previous
//
#include <hip/hip_runtime.h>
#include <hip/hip_bf16.h>
#include <stdint.h>

// AutoregressiveDense: B=8192, D=1024, STRIDE=16, OUT=64, L=64
#define BROWS 8192
#define DDIM  1024
#define LDIM  64
#define ODIM  64
#define NDIM  4096
#define KSTRIDE 16

typedef __attribute__((ext_vector_type(8))) short bf16x8;           // MFMA A/B frag
typedef __attribute__((ext_vector_type(4))) float f32x4;            // MFMA C/D frag
typedef __attribute__((ext_vector_type(8))) unsigned short u16x8;   // 16B bf16 store

static __device__ __forceinline__ unsigned short f2bf(float f) {
    union { float f; uint32_t u; } v; v.f = f;
    uint32_t r = 0x7FFFu + ((v.u >> 16) & 1u);
    return (unsigned short)((v.u + r) >> 16);
}

static __device__ __forceinline__ void async16(const void* g, void* l) {
    __builtin_amdgcn_global_load_lds(
        (const __attribute__((address_space(1))) void*)g,
        (__attribute__((address_space(3))) void*)l, 16, 0, 0);
}

// ---------- merged prep: blocks [0,1024) build masked W' (B^T bf16), blocks [1024,5120) convert x ----------
__global__ __launch_bounds__(256) void prep_kernel(const float* __restrict__ x,
                                                   const float* __restrict__ W,
                                                   unsigned short* __restrict__ xb,
                                                   unsigned short* __restrict__ wbt) {
    const int bid = blockIdx.x;
    if (bid < 1024) {
        // W [L][D][O] f32 -> masked bf16 W' [N=l*64+o][K=d], zero for d >= l*16
        __shared__ float tile[64][65];
        const int l  = bid >> 4;
        const int d0 = (bid & 15) << 6;
        const int t  = threadIdx.x;
        {
            const int dd = t >> 2;
            const int o4 = (t & 3) << 4;
            const float* src = W + ((size_t)((l << 10) + d0 + dd) << 6) + o4;
            #pragma unroll
            for (int j = 0; j < 4; ++j) {
                float4 v = reinterpret_cast<const float4*>(src)[j];
                tile[dd][o4 + 4 * j + 0] = v.x;
                tile[dd][o4 + 4 * j + 1] = v.y;
                tile[dd][o4 + 4 * j + 2] = v.z;
                tile[dd][o4 + 4 * j + 3] = v.w;
            }
        }
        __syncthreads();
        {
            const int o    = t >> 2;
            const int dloc = (t & 3) << 4;
            const int kmax = l * KSTRIDE;
            unsigned short* dst = wbt + ((size_t)((l << 6) + o) << 10) + d0 + dloc;
            u16x8 r0, r1;
            #pragma unroll
            for (int j = 0; j < 8; ++j) {
                int da = d0 + dloc + j;
                int db = da + 8;
                r0[j] = (da < kmax) ? f2bf(tile[dloc + j][o])     : (unsigned short)0;
                r1[j] = (db < kmax) ? f2bf(tile[dloc + 8 + j][o]) : (unsigned short)0;
            }
            *reinterpret_cast<u16x8*>(dst)     = r0;
            *reinterpret_cast<u16x8*>(dst + 8) = r1;
        }
    } else {
        int i = (bid - 1024) * 256 + threadIdx.x;
        const float4* xf = reinterpret_cast<const float4*>(x);
        float4 v0 = xf[2 * i];
        float4 v1 = xf[2 * i + 1];
        u16x8 r;
        r[0] = f2bf(v0.x); r[1] = f2bf(v0.y); r[2] = f2bf(v0.z); r[3] = f2bf(v0.w);
        r[4] = f2bf(v1.x); r[5] = f2bf(v1.y); r[6] = f2bf(v1.z); r[7] = f2bf(v1.w);
        reinterpret_cast<u16x8*>(xb)[i] = r;
    }
}

// ---------- main GEMM: 256x128 tile, BK=32, 8 waves (4Mx2N, wave tile 64x64) ----------
// 2-phase double-buffered K-loop (T3-lite): stage(t+1) at iter TOP -> loads age under
// ds_read+16 MFMA (~400cyc) -> ONE __syncthreads per step (its vmcnt(0) sees aged loads).
// r1/r5 paid two barriers + a zero-age vmcnt(0) drain per step (L2 latency exposed每step).
// acc[4][4]=64 regs (proven footprint, fits the 128-VGPR (512,2) cap; no spill).
// LDS 2 x (A 16KB + B 8KB) = 48KB -> 2 blocks/CU. Supertile XCD mapping kept from r5.
__global__ __launch_bounds__(512, 2) void ar_gemm_kernel(
        const unsigned short* __restrict__ xb,
        const unsigned short* __restrict__ wbt,
        const float* __restrict__ bias,
        float* __restrict__ out) {
    __shared__ char lds[49152];   // buf p at p*24576: A[256][64B] at +0, B[128][64B] at +16384

    const int s  = blockIdx.x >> 8;            // 4 supertiles of 256 blocks (one generation each)
    const int i  = blockIdx.x & 255;
    const int bm = ((s & 1) << 4) + (i & 15);          // 0..31 (tiles of 256 rows)
    const int bn = ((s < 2) ? 16 : 0) + 15 - (i >> 4); // heavy bn (16..31) first, big nkt first
    const int tid  = threadIdx.x;
    const int lane = tid & 63;
    const int wid  = tid >> 6;
    const int wm   = wid >> 1;                 // 4 M-waves x 2 N-waves, wave tile 64x64
    const int wn   = wid & 1;

    const int nkt = bn + 1;                    // ceil((2bn+1)*16 / 32) K-tiles of 32

    // staging: thread t -> row t>>2, 16B chunk (t&3) of the 64B k-row; LDS linear t*16
    const int cb = (tid & 3) << 4;
    const char* gA = (const char*)xb  + ((size_t)((bm << 8) + (tid >> 2)) << 11) + cb;
    const char* gB = (const char*)wbt + ((size_t)((bn << 7) + (tid >> 2)) << 11) + cb;

    // fragment read offsets (bytes): row = (lane&15), k-granule by lane>>4 (r1-proven layout)
    const int aoff = ((wm << 6) + (lane & 15)) * 64 + ((lane >> 4) << 4);
    const int boff = 16384 + ((wn << 6) + (lane & 15)) * 64 + ((lane >> 4) << 4);

    f32x4 acc[4][4];
    #pragma unroll
    for (int m = 0; m < 4; ++m)
        #pragma unroll
        for (int n = 0; n < 4; ++n)
            acc[m][n] = (f32x4)(0.f);

    // stage K-tile t into buffer p (3 asyncs/thread: A-half0, A-half1, B). Clamp source for t>=nkt.
    auto stage = [&](int t, int p) {
        const int kb = (t < nkt ? t : nkt - 1) << 6;
        char* l = lds + p * 24576 + tid * 16;
        async16(gA + kb, l);
        async16(gA + ((size_t)128 << 11) + kb, l + 8192);
        async16(gB + kb, l + 16384);
    };

    stage(0, 0);
    __syncthreads();                           // vmcnt(0)+barrier: tile0 ready

    for (int t = 0; t < nkt; ++t) {
        const int p = t & 1;
        stage(t + 1, p ^ 1);                   // prefetch next tile; ages under compute below
        const char* pb = lds + p * 24576;
        bf16x8 a[4], b[4];
        #pragma unroll
        for (int m = 0; m < 4; ++m)
            a[m] = *reinterpret_cast<const bf16x8*>(pb + aoff + m * 1024);
        #pragma unroll
        for (int n = 0; n < 4; ++n)
            b[n] = *reinterpret_cast<const bf16x8*>(pb + boff + n * 1024);
        #pragma unroll
        for (int m = 0; m < 4; ++m)
            #pragma unroll
            for (int n = 0; n < 4; ++n)
                acc[m][n] = __builtin_amdgcn_mfma_f32_16x16x32_bf16(a[m], b[n], acc[m][n], 0, 0, 0);
        __syncthreads();                       // one barrier/step; drains prefetch (aged) + WAR on LDS
    }

    // epilogue: C/D layout col=lane&15, row=(lane>>4)*4+j; add bias in f32
    const int crow = (bm << 8) + (wm << 6) + ((lane >> 4) << 2);
    const int ccol = (bn << 7) + (wn << 6) + (lane & 15);
    float bv[4];
    #pragma unroll
    for (int n = 0; n < 4; ++n) bv[n] = bias[ccol + n * 16];
    #pragma unroll
    for (int m = 0; m < 4; ++m)
        #pragma unroll
        for (int n = 0; n < 4; ++n)
            #pragma unroll
            for (int j = 0; j < 4; ++j)
                out[(size_t)(crow + m * 16 + j) * NDIM + ccol + n * 16] = acc[m][n][j] + bv[n];
}

// ---------- fallback: naive f32 (used only if workspace too small) ----------
__global__ __launch_bounds__(256) void naive_kernel(const float* __restrict__ x,
                                                    const float* __restrict__ W,
                                                    const float* __restrict__ bias,
                                                    float* __restrict__ out) {
    size_t idx = (size_t)blockIdx.x * 256 + threadIdx.x;
    if (idx >= (size_t)BROWS * NDIM) return;
    int m = (int)(idx >> 12);
    int n = (int)(idx & 4095);
    int l = n >> 6;
    int o = n & 63;
    int kmax = l * KSTRIDE;
    float s = bias[n];
    const float* xr = x + (size_t)m * DDIM;
    const float* wp = W + ((size_t)l << 16) + o;
    for (int d = 0; d < kmax; ++d) s += xr[d] * wp[(size_t)d << 6];
    out[idx] = s;
}

extern "C" void kernel_launch(void* const* d_in, const int* in_sizes, int n_in,
                              void* d_out, int out_size, void* d_ws, size_t ws_size,
                              hipStream_t stream) {
    const float* x = (const float*)d_in[0];
    const float* W = (const float*)d_in[1];
    const float* b = (const float*)d_in[2];
    float* out = (float*)d_out;

    const size_t need = ((size_t)BROWS * DDIM + (size_t)NDIM * DDIM) * sizeof(unsigned short);
    if (ws_size < need) {
        int total = BROWS * NDIM;
        naive_kernel<<<(total + 255) / 256, 256, 0, stream>>>(x, W, b, out);
        return;
    }
    unsigned short* xbuf = (unsigned short*)d_ws;             // bf16 x  [8192][1024]
    unsigned short* wbt  = xbuf + (size_t)BROWS * DDIM;       // bf16 W' [4096][1024]

    prep_kernel<<<5120, 256, 0, stream>>>(x, W, xbuf, wbt);
    ar_gemm_kernel<<<1024, 512, 0, stream>>>(xbuf, wbt, b, out);
}

// Round 7
// 62.665 us; speedup vs baseline: 3.1744x; 1.0211x over previous
//
#include <hip/hip_runtime.h>
#include <hip/hip_bf16.h>
#include <stdint.h>

// AutoregressiveDense: B=8192, D=1024, STRIDE=16, OUT=64, L=64
#define BROWS 8192
#define DDIM  1024
#define LDIM  64
#define ODIM  64
#define NDIM  4096
#define KSTRIDE 16

typedef __attribute__((ext_vector_type(8))) short bf16x8;           // MFMA A/B frag
typedef __attribute__((ext_vector_type(4))) float f32x4;            // MFMA C/D frag
typedef __attribute__((ext_vector_type(8))) unsigned short u16x8;   // 16B bf16 store

static __device__ __forceinline__ unsigned short f2bf(float f) {
    union { float f; uint32_t u; } v; v.f = f;
    uint32_t r = 0x7FFFu + ((v.u >> 16) & 1u);
    return (unsigned short)((v.u + r) >> 16);
}

static __device__ __forceinline__ void async16(const void* g, void* l) {
    __builtin_amdgcn_global_load_lds(
        (const __attribute__((address_space(1))) void*)g,
        (__attribute__((address_space(3))) void*)l, 16, 0, 0);
}

// ---------- merged prep: blocks [0,1024) build masked W' (B^T bf16), blocks [1024,5120) convert x ----------
__global__ __launch_bounds__(256) void prep_kernel(const float* __restrict__ x,
                                                   const float* __restrict__ W,
                                                   unsigned short* __restrict__ xb,
                                                   unsigned short* __restrict__ wbt) {
    const int bid = blockIdx.x;
    if (bid < 1024) {
        // W [L][D][O] f32 -> masked bf16 W' [N=l*64+o][K=d], zero for d >= l*16
        __shared__ float tile[64][65];
        const int l  = bid >> 4;
        const int d0 = (bid & 15) << 6;
        const int t  = threadIdx.x;
        {
            const int dd = t >> 2;
            const int o4 = (t & 3) << 4;
            const float* src = W + ((size_t)((l << 10) + d0 + dd) << 6) + o4;
            #pragma unroll
            for (int j = 0; j < 4; ++j) {
                float4 v = reinterpret_cast<const float4*>(src)[j];
                tile[dd][o4 + 4 * j + 0] = v.x;
                tile[dd][o4 + 4 * j + 1] = v.y;
                tile[dd][o4 + 4 * j + 2] = v.z;
                tile[dd][o4 + 4 * j + 3] = v.w;
            }
        }
        __syncthreads();
        {
            const int o    = t >> 2;
            const int dloc = (t & 3) << 4;
            const int kmax = l * KSTRIDE;
            unsigned short* dst = wbt + ((size_t)((l << 6) + o) << 10) + d0 + dloc;
            u16x8 r0, r1;
            #pragma unroll
            for (int j = 0; j < 8; ++j) {
                int da = d0 + dloc + j;
                int db = da + 8;
                r0[j] = (da < kmax) ? f2bf(tile[dloc + j][o])     : (unsigned short)0;
                r1[j] = (db < kmax) ? f2bf(tile[dloc + 8 + j][o]) : (unsigned short)0;
            }
            *reinterpret_cast<u16x8*>(dst)     = r0;
            *reinterpret_cast<u16x8*>(dst + 8) = r1;
        }
    } else {
        int i = (bid - 1024) * 256 + threadIdx.x;
        const float4* xf = reinterpret_cast<const float4*>(x);
        float4 v0 = xf[2 * i];
        float4 v1 = xf[2 * i + 1];
        u16x8 r;
        r[0] = f2bf(v0.x); r[1] = f2bf(v0.y); r[2] = f2bf(v0.z); r[3] = f2bf(v0.w);
        r[4] = f2bf(v1.x); r[5] = f2bf(v1.y); r[6] = f2bf(v1.z); r[7] = f2bf(v1.w);
        reinterpret_cast<u16x8*>(xb)[i] = r;
    }
}

// ---------- main GEMM: 256x128 tile, BK=32, 8 waves (4Mx2N, wave tile 64x64) ----------
// Distance-2 triple-buffered pipeline (T4): prologue stages tiles 0,1; iter t waits
// vmcnt(3) (= tile t's loads ONLY; tile t+1 stays in flight ACROSS the raw s_barrier),
// then stages t+2, then computes t. Loads age 2 full iterations (~1200cy) -> HBM latency
// hidden. r5/r6's single/double-barrier loops both exposed ~500cy/step residual latency
// (measured-neutral r5->r6 confirmed the model). NO __syncthreads in the loop (it would
// emit the vmcnt(0)-drain structural stall). WAR safe: stage(t+2) writes buf[(t-1)%3],
// whose readers all passed this iter's barrier.
// LDS 3 x 24KB = 72KB -> 2 blocks/CU. acc[4][4]=64 regs. Supertile XCD mapping kept.
__global__ __launch_bounds__(512, 2) void ar_gemm_kernel(
        const unsigned short* __restrict__ xb,
        const unsigned short* __restrict__ wbt,
        const float* __restrict__ bias,
        float* __restrict__ out) {
    __shared__ char lds[73728];   // buf p at p*24576: A[256][64B] at +0, B[128][64B] at +16384

    const int s  = blockIdx.x >> 8;            // 4 supertiles of 256 blocks (one generation each)
    const int i  = blockIdx.x & 255;
    const int bm = ((s & 1) << 4) + (i & 15);          // 0..31 (tiles of 256 rows)
    const int bn = ((s < 2) ? 16 : 0) + 15 - (i >> 4); // heavy bn (16..31) first, big nkt first
    const int tid  = threadIdx.x;
    const int lane = tid & 63;
    const int wid  = tid >> 6;
    const int wm   = wid >> 1;                 // 4 M-waves x 2 N-waves, wave tile 64x64
    const int wn   = wid & 1;

    const int nkt = bn + 1;                    // ceil((2bn+1)*16 / 32) K-tiles of 32

    // staging: thread t -> row t>>2, 16B chunk (t&3) of the 64B k-row; LDS linear t*16
    const int cb = (tid & 3) << 4;
    const char* gA = (const char*)xb  + ((size_t)((bm << 8) + (tid >> 2)) << 11) + cb;
    const char* gB = (const char*)wbt + ((size_t)((bn << 7) + (tid >> 2)) << 11) + cb;

    // fragment read offsets (bytes): row = (lane&15), k-granule by lane>>4 (r1-proven layout)
    const int aoff = ((wm << 6) + (lane & 15)) * 64 + ((lane >> 4) << 4);
    const int boff = 16384 + ((wn << 6) + (lane & 15)) * 64 + ((lane >> 4) << 4);

    f32x4 acc[4][4];
    #pragma unroll
    for (int m = 0; m < 4; ++m)
        #pragma unroll
        for (int n = 0; n < 4; ++n)
            acc[m][n] = (f32x4)(0.f);

    // stage K-tile t into buffer t%3 (3 asyncs/thread). Clamp source for t>=nkt (dest unused).
    auto stage = [&](int t) {
        const int kb = (t < nkt ? t : nkt - 1) << 6;
        char* l = lds + (t % 3) * 24576 + tid * 16;
        async16(gA + kb, l);
        async16(gA + ((size_t)128 << 11) + kb, l + 8192);
        async16(gB + kb, l + 16384);
    };

    stage(0);
    stage(1);                                  // 6 loads in flight

    for (int t = 0; t < nkt; ++t) {
        asm volatile("s_waitcnt vmcnt(3)" ::: "memory");   // tile t landed; t+1 stays in flight
        __builtin_amdgcn_sched_barrier(0);
        __builtin_amdgcn_s_barrier();                      // raw: no vmcnt(0) drain
        stage(t + 2);                                      // writes buf[(t-1)%3]; readers passed barrier
        const char* pb = lds + (t % 3) * 24576;
        bf16x8 a[4], b[4];
        #pragma unroll
        for (int m = 0; m < 4; ++m)
            a[m] = *reinterpret_cast<const bf16x8*>(pb + aoff + m * 1024);
        #pragma unroll
        for (int n = 0; n < 4; ++n)
            b[n] = *reinterpret_cast<const bf16x8*>(pb + boff + n * 1024);
        #pragma unroll
        for (int m = 0; m < 4; ++m)
            #pragma unroll
            for (int n = 0; n < 4; ++n)
                acc[m][n] = __builtin_amdgcn_mfma_f32_16x16x32_bf16(a[m], b[n], acc[m][n], 0, 0, 0);
    }
    asm volatile("s_waitcnt vmcnt(0)" ::: "memory");       // drain clamped tails before LDS dealloc

    // epilogue: C/D layout col=lane&15, row=(lane>>4)*4+j; add bias in f32
    const int crow = (bm << 8) + (wm << 6) + ((lane >> 4) << 2);
    const int ccol = (bn << 7) + (wn << 6) + (lane & 15);
    float bv[4];
    #pragma unroll
    for (int n = 0; n < 4; ++n) bv[n] = bias[ccol + n * 16];
    #pragma unroll
    for (int m = 0; m < 4; ++m)
        #pragma unroll
        for (int n = 0; n < 4; ++n)
            #pragma unroll
            for (int j = 0; j < 4; ++j)
                out[(size_t)(crow + m * 16 + j) * NDIM + ccol + n * 16] = acc[m][n][j] + bv[n];
}

// ---------- fallback: naive f32 (used only if workspace too small) ----------
__global__ __launch_bounds__(256) void naive_kernel(const float* __restrict__ x,
                                                    const float* __restrict__ W,
                                                    const float* __restrict__ bias,
                                                    float* __restrict__ out) {
    size_t idx = (size_t)blockIdx.x * 256 + threadIdx.x;
    if (idx >= (size_t)BROWS * NDIM) return;
    int m = (int)(idx >> 12);
    int n = (int)(idx & 4095);
    int l = n >> 6;
    int o = n & 63;
    int kmax = l * KSTRIDE;
    float s = bias[n];
    const float* xr = x + (size_t)m * DDIM;
    const float* wp = W + ((size_t)l << 16) + o;
    for (int d = 0; d < kmax; ++d) s += xr[d] * wp[(size_t)d << 6];
    out[idx] = s;
}

extern "C" void kernel_launch(void* const* d_in, const int* in_sizes, int n_in,
                              void* d_out, int out_size, void* d_ws, size_t ws_size,
                              hipStream_t stream) {
    const float* x = (const float*)d_in[0];
    const float* W = (const float*)d_in[1];
    const float* b = (const float*)d_in[2];
    float* out = (float*)d_out;

    const size_t need = ((size_t)BROWS * DDIM + (size_t)NDIM * DDIM) * sizeof(unsigned short);
    if (ws_size < need) {
        int total = BROWS * NDIM;
        naive_kernel<<<(total + 255) / 256, 256, 0, stream>>>(x, W, b, out);
        return;
    }
    unsigned short* xbuf = (unsigned short*)d_ws;             // bf16 x  [8192][1024]
    unsigned short* wbt  = xbuf + (size_t)BROWS * DDIM;       // bf16 W' [4096][1024]

    prep_kernel<<<5120, 256, 0, stream>>>(x, W, xbuf, wbt);
    ar_gemm_kernel<<<1024, 512, 0, stream>>>(xbuf, wbt, b, out);
}